// Round 3
// baseline (704.986 us; speedup 1.0000x reference)
//
#include <hip/hip_runtime.h>
#include <hip/hip_bf16.h>
#include <stdint.h>

#define N_NODES 50000
#define N_EDGES 800000
#define D_IN 128
#define D_HID 256
#define D_OUT 128
#define LAYERS 3

typedef __attribute__((ext_vector_type(8))) short bf16x8;   // 8 bf16 = 4 VGPRs (MFMA A/B frag)
typedef __attribute__((ext_vector_type(4))) float f32x4;    // MFMA C/D frag
typedef __attribute__((ext_vector_type(4))) unsigned short us4;
typedef __attribute__((ext_vector_type(8))) unsigned short us8;

static __device__ __forceinline__ unsigned short f2bf(float f) {
  union { float f; unsigned int u; } v; v.f = f;
  unsigned int r = v.u + 0x7fff + ((v.u >> 16) & 1);   // RNE
  return (unsigned short)(r >> 16);
}

// ---------------------------------------------------------------------------
// CSR build: histogram of dst -> exclusive scan -> slot fill.
// Rebuilt every launch (ws is re-poisoned); ~30-40us total, replaces 307M
// f32 atomics with 1.6M int atomics.
// ---------------------------------------------------------------------------
__global__ __launch_bounds__(256) void hist_kernel(
    const int* __restrict__ dst, int* __restrict__ deg) {
  int e = blockIdx.x * 256 + threadIdx.x;
  if (e < N_EDGES) atomicAdd(&deg[dst[e]], 1);
}

// Single-block exclusive scan over deg[50000] -> rowptr[50001], cursor copy.
#define SCAN_T 1024
#define SCAN_CH 49   // 1024*49 = 50176 >= 50001
__global__ __launch_bounds__(SCAN_T) void scan_kernel(
    const int* __restrict__ deg, int* __restrict__ rowptr,
    int* __restrict__ cursor) {
  __shared__ int part[SCAN_T];
  const int tid = threadIdx.x;
  const int base = tid * SCAN_CH;
  int ssum = 0;
#pragma unroll
  for (int i = 0; i < SCAN_CH; ++i) {
    int idx = base + i;
    ssum += (idx < N_NODES) ? deg[idx] : 0;
  }
  part[tid] = ssum;
  __syncthreads();
  for (int off = 1; off < SCAN_T; off <<= 1) {
    int add = 0;
    if (tid >= off) add = part[tid - off];
    __syncthreads();
    if (tid >= off) part[tid] += add;
    __syncthreads();
  }
  int run = (tid == 0) ? 0 : part[tid - 1];
#pragma unroll
  for (int i = 0; i < SCAN_CH; ++i) {
    int idx = base + i;
    if (idx <= N_NODES) {
      rowptr[idx] = run;
      if (idx < N_NODES) {
        cursor[idx] = run;
        run += deg[idx];
      }
    }
  }
}

__global__ __launch_bounds__(256) void fill_kernel(
    const int* __restrict__ src, const int* __restrict__ dst,
    int* __restrict__ cursor, int* __restrict__ eidx) {
  int e = blockIdx.x * 256 + threadIdx.x;
  if (e >= N_EDGES) return;
  int pos = atomicAdd(&cursor[dst[e]], 1);
  eidx[pos] = src[e];
}

// ---------------------------------------------------------------------------
// Aggregation: agg[n] = x[n] + sum_{j in CSR[n]} x[eidx[j]].  No atomics.
// 128 threads (2 waves) per node, thread t owns feature t; row gathers are
// 512B coalesced, served from L2/L3 (x = 25.6MB, L3-resident).
// ---------------------------------------------------------------------------
__global__ __launch_bounds__(256) void agg_kernel(
    const float* __restrict__ x, const int* __restrict__ rowptr,
    const int* __restrict__ eidx, float* __restrict__ agg) {
  int n = blockIdx.x * 2 + (threadIdx.x >> 7);
  if (n >= N_NODES) return;
  int t = threadIdx.x & 127;
  float acc = x[(size_t)n * D_IN + t];
  int j = rowptr[n];
  const int end = rowptr[n + 1];
  for (; j + 1 < end; j += 2) {          // 2-unrolled: overlap the two gathers
    int s0 = eidx[j], s1 = eidx[j + 1];
    float v0 = x[(size_t)s0 * D_IN + t];
    float v1 = x[(size_t)s1 * D_IN + t];
    acc += v0; acc += v1;
  }
  if (j < end) acc += x[(size_t)eidx[j] * D_IN + t];
  agg[(size_t)n * D_IN + t] = acc;
}

// ---------------------------------------------------------------------------
// Convert W1 [L][K=128][N=256] and W2 [L][K=256][N=128] (f32) to bf16,
// TRANSPOSED to [L][N][K] so MFMA B-fragments are 16B-contiguous loads.
// ---------------------------------------------------------------------------
__global__ __launch_bounds__(256) void convert_weights(
    const float* __restrict__ W1, const float* __restrict__ W2,
    unsigned short* __restrict__ w1bf, unsigned short* __restrict__ w2bf) {
  int idx = blockIdx.x * 256 + threadIdx.x;
  const int per = LAYERS * D_IN * D_HID;   // 98304 (same count for both)
  if (idx < per) {
    int l = idx / (D_IN * D_HID);
    int r = idx % (D_IN * D_HID);
    int n = r / D_IN;        // 0..255
    int k = r % D_IN;        // 0..127
    w1bf[idx] = f2bf(W1[(size_t)l * D_IN * D_HID + (size_t)k * D_HID + n]);
  } else {
    int j = idx - per;
    if (j < LAYERS * D_HID * D_OUT) {
      int l = j / (D_HID * D_OUT);
      int r = j % (D_HID * D_OUT);
      int n = r / D_HID;     // 0..127
      int k = r % D_HID;     // 0..255
      w2bf[j] = f2bf(W2[(size_t)l * D_HID * D_OUT + (size_t)k * D_OUT + n]);
    }
  }
}

// ---------------------------------------------------------------------------
// MLP layer 1: h = relu(agg @ W1 + b1).  M=50000, N=256, K=128.
// Block = 256 thr (4 waves), tile 64x256; wave w handles cols [w*64, w*64+64).
// A staged bf16 in LDS [64][136] (pad 8 -> max 2-way bank alias, free).
// ---------------------------------------------------------------------------
#define LDA1 136
__global__ __launch_bounds__(256) void mlp1_kernel(
    const float* __restrict__ agg, const unsigned short* __restrict__ w1,
    const float* __restrict__ b1, unsigned short* __restrict__ h) {
  __shared__ unsigned short As[64 * LDA1];
  const int tid = threadIdx.x;
  const int block_row = blockIdx.x * 64;

  // Stage A: 64 rows x 128 f32 -> bf16.  2048 float4 loads, coalesced.
  for (int k = 0; k < 8; ++k) {
    int j = tid + k * 256;           // float4 index, 32 per row
    int row = j >> 5;
    int c4 = j & 31;
    int node = block_row + row;
    if (node >= N_NODES) node = N_NODES - 1;   // clamp; garbage rows never stored
    float4 v = ((const float4*)agg)[(size_t)node * 32 + c4];
    us4 p = { f2bf(v.x), f2bf(v.y), f2bf(v.z), f2bf(v.w) };
    *(us4*)&As[row * LDA1 + c4 * 4] = p;
  }
  __syncthreads();

  const int wave = tid >> 6;
  const int lane = tid & 63;
  const int lo16 = lane & 15;
  const int hi4  = lane >> 4;
  const int ncol0 = wave * 64;

  f32x4 acc[4][4] = {};
  for (int ks = 0; ks < 4; ++ks) {
    const int koff = ks * 32 + hi4 * 8;
    bf16x8 a[4], b[4];
#pragma unroll
    for (int m = 0; m < 4; ++m)
      a[m] = *(const bf16x8*)&As[(m * 16 + lo16) * LDA1 + koff];
#pragma unroll
    for (int n = 0; n < 4; ++n)
      b[n] = *(const bf16x8*)&w1[(size_t)(ncol0 + n * 16 + lo16) * D_IN + koff];
#pragma unroll
    for (int m = 0; m < 4; ++m)
#pragma unroll
      for (int n = 0; n < 4; ++n)
        acc[m][n] = __builtin_amdgcn_mfma_f32_16x16x32_bf16(a[m], b[n], acc[m][n], 0, 0, 0);
  }

#pragma unroll
  for (int n = 0; n < 4; ++n) {
    int col = ncol0 + n * 16 + lo16;
    float bias = b1[col];
#pragma unroll
    for (int m = 0; m < 4; ++m) {
#pragma unroll
      for (int r = 0; r < 4; ++r) {
        int node = block_row + m * 16 + hi4 * 4 + r;
        if (node < N_NODES) {
          float v = acc[m][n][r] + bias;
          v = v > 0.f ? v : 0.f;
          h[(size_t)node * D_HID + col] = f2bf(v);
        }
      }
    }
  }
}

// ---------------------------------------------------------------------------
// MLP layer 2: out = h @ W2 + b2.  M=50000, N=128, K=256.
// Block = 256 thr, tile 64x128; wave w handles cols [w*32, w*32+32).
// ---------------------------------------------------------------------------
#define LDA2 264
__global__ __launch_bounds__(256) void mlp2_kernel(
    const unsigned short* __restrict__ h, const unsigned short* __restrict__ w2,
    const float* __restrict__ b2, float* __restrict__ out) {
  __shared__ unsigned short As[64 * LDA2];
  const int tid = threadIdx.x;
  const int block_row = blockIdx.x * 64;

  // Stage A: 64 rows x 256 bf16.  2048 us8 (16B) loads, coalesced.
  for (int k = 0; k < 8; ++k) {
    int j = tid + k * 256;           // us8 index, 32 per row
    int row = j >> 5;
    int c8 = j & 31;
    int node = block_row + row;
    if (node >= N_NODES) node = N_NODES - 1;
    us8 v = *(const us8*)&h[(size_t)node * D_HID + c8 * 8];
    *(us8*)&As[row * LDA2 + c8 * 8] = v;
  }
  __syncthreads();

  const int wave = tid >> 6;
  const int lane = tid & 63;
  const int lo16 = lane & 15;
  const int hi4  = lane >> 4;
  const int ncol0 = wave * 32;

  f32x4 acc[4][2] = {};
  for (int ks = 0; ks < 8; ++ks) {
    const int koff = ks * 32 + hi4 * 8;
    bf16x8 a[4], b[2];
#pragma unroll
    for (int m = 0; m < 4; ++m)
      a[m] = *(const bf16x8*)&As[(m * 16 + lo16) * LDA2 + koff];
#pragma unroll
    for (int n = 0; n < 2; ++n)
      b[n] = *(const bf16x8*)&w2[(size_t)(ncol0 + n * 16 + lo16) * D_HID + koff];
#pragma unroll
    for (int m = 0; m < 4; ++m)
#pragma unroll
      for (int n = 0; n < 2; ++n)
        acc[m][n] = __builtin_amdgcn_mfma_f32_16x16x32_bf16(a[m], b[n], acc[m][n], 0, 0, 0);
  }

#pragma unroll
  for (int n = 0; n < 2; ++n) {
    int col = ncol0 + n * 16 + lo16;
    float bias = b2[col];
#pragma unroll
    for (int m = 0; m < 4; ++m) {
#pragma unroll
      for (int r = 0; r < 4; ++r) {
        int node = block_row + m * 16 + hi4 * 4 + r;
        if (node < N_NODES)
          out[(size_t)node * D_OUT + col] = acc[m][n][r] + bias;
      }
    }
  }
}

// ---------------------------------------------------------------------------
extern "C" void kernel_launch(void* const* d_in, const int* in_sizes, int n_in,
                              void* d_out, int out_size, void* d_ws, size_t ws_size,
                              hipStream_t stream) {
  const float* x0 = (const float*)d_in[0];
  const float* W1 = (const float*)d_in[1];
  const float* b1 = (const float*)d_in[2];
  const float* W2 = (const float*)d_in[3];
  const float* b2 = (const float*)d_in[4];
  const int* src  = (const int*)d_in[5];
  const int* dst  = (const int*)d_in[6];
  float* out = (float*)d_out;

  char* ws = (char*)d_ws;
  size_t off = 0;
  float* agg = (float*)(ws + off);            off += (size_t)N_NODES * D_IN * 4;   // 25.6 MB
  unsigned short* hbuf = (unsigned short*)(ws + off); off += (size_t)N_NODES * D_HID * 2; // 25.6 MB
  float* xbuf = (float*)(ws + off);           off += (size_t)N_NODES * D_OUT * 4;  // 25.6 MB
  unsigned short* w1bf = (unsigned short*)(ws + off); off += (size_t)LAYERS * D_IN * D_HID * 2;
  unsigned short* w2bf = (unsigned short*)(ws + off); off += (size_t)LAYERS * D_HID * D_OUT * 2;
  int* deg    = (int*)(ws + off); off += (size_t)(N_NODES + 1) * 4;
  int* rowptr = (int*)(ws + off); off += (size_t)(N_NODES + 1) * 4;
  int* cursor = (int*)(ws + off); off += (size_t)(N_NODES + 1) * 4;
  int* eidx   = (int*)(ws + off); off += (size_t)N_EDGES * 4;       // 3.2 MB

  // --- CSR build (per launch; ws is re-poisoned each call) ---
  hipMemsetAsync(deg, 0, (size_t)N_NODES * 4, stream);
  hist_kernel<<<N_EDGES / 256, 256, 0, stream>>>(dst, deg);
  scan_kernel<<<1, SCAN_T, 0, stream>>>(deg, rowptr, cursor);
  fill_kernel<<<N_EDGES / 256, 256, 0, stream>>>(src, dst, cursor, eidx);

  convert_weights<<<768, 256, 0, stream>>>(W1, W2, w1bf, w2bf);

  const int grid_mlp = (N_NODES + 63) / 64;   // 782
  const int grid_agg = (N_NODES + 1) / 2;     // 25000
  const float* xcur = x0;
  for (int l = 0; l < LAYERS; ++l) {
    agg_kernel<<<grid_agg, 256, 0, stream>>>(xcur, rowptr, eidx, agg);
    mlp1_kernel<<<grid_mlp, 256, 0, stream>>>(
        agg, w1bf + (size_t)l * D_IN * D_HID, b1 + (size_t)l * D_HID, hbuf);
    float* xo = (l == LAYERS - 1) ? out : xbuf;
    mlp2_kernel<<<grid_mlp, 256, 0, stream>>>(
        hbuf, w2bf + (size_t)l * D_HID * D_OUT, b2 + (size_t)l * D_OUT, xo);
    xcur = xbuf;
  }
}

// Round 7
// 438.797 us; speedup vs baseline: 1.6066x; 1.6066x over previous
//
#include <hip/hip_runtime.h>
#include <hip/hip_bf16.h>
#include <stdint.h>

#define N_NODES 50000
#define N_EDGES 800000
#define D_IN 128
#define D_HID 256
#define D_OUT 128
#define LAYERS 3

typedef __attribute__((ext_vector_type(8))) short bf16x8;   // 8 bf16 = 4 VGPRs (MFMA A/B frag)
typedef __attribute__((ext_vector_type(4))) float f32x4;    // MFMA C/D frag
typedef __attribute__((ext_vector_type(4))) unsigned short us4;
typedef __attribute__((ext_vector_type(8))) unsigned short us8;

static __device__ __forceinline__ unsigned short f2bf(float f) {
  union { float f; unsigned int u; } v; v.f = f;
  unsigned int r = v.u + 0x7fff + ((v.u >> 16) & 1);   // RNE
  return (unsigned short)(r >> 16);
}
static __device__ __forceinline__ float bf2f(unsigned short u) {
  union { unsigned int u; float f; } v; v.u = ((unsigned int)u) << 16;
  return v.f;
}

// ---------------------------------------------------------------------------
// CSR build: histogram of dst -> 3-phase multi-block exclusive scan -> fill.
// ---------------------------------------------------------------------------
__global__ __launch_bounds__(256) void hist_kernel(
    const int* __restrict__ dst, int* __restrict__ deg) {
  int e = blockIdx.x * 256 + threadIdx.x;
  if (e < N_EDGES) atomicAdd(&deg[dst[e]], 1);
}

#define SCAN_BLOCKS 196   // 196*256 = 50176 >= 50000

// Phase A: per-block exclusive scan of deg -> rowptr (local), block sums -> partial.
__global__ __launch_bounds__(256) void scan_a_kernel(
    const int* __restrict__ deg, int* __restrict__ rowptr,
    int* __restrict__ partial) {
  __shared__ int buf[256];
  const int tid = threadIdx.x;
  int gid = blockIdx.x * 256 + tid;
  int v = (gid < N_NODES) ? deg[gid] : 0;
  buf[tid] = v;
  __syncthreads();
  for (int off = 1; off < 256; off <<= 1) {
    int add = (tid >= off) ? buf[tid - off] : 0;
    __syncthreads();
    buf[tid] += add;
    __syncthreads();
  }
  if (gid < N_NODES) rowptr[gid] = buf[tid] - v;   // exclusive, local
  if (tid == 255) partial[blockIdx.x] = buf[255];
}

// Phase B: single-block exclusive scan of partial[SCAN_BLOCKS] in place.
__global__ __launch_bounds__(256) void scan_b_kernel(int* __restrict__ partial) {
  __shared__ int buf[256];
  const int tid = threadIdx.x;
  int v = (tid < SCAN_BLOCKS) ? partial[tid] : 0;
  buf[tid] = v;
  __syncthreads();
  for (int off = 1; off < 256; off <<= 1) {
    int add = (tid >= off) ? buf[tid - off] : 0;
    __syncthreads();
    buf[tid] += add;
    __syncthreads();
  }
  if (tid < SCAN_BLOCKS) partial[tid] = buf[tid] - v;  // exclusive
}

// Phase C: add block offsets; copy to cursor; set rowptr[N] = E.
__global__ __launch_bounds__(256) void scan_c_kernel(
    int* __restrict__ rowptr, const int* __restrict__ partial,
    int* __restrict__ cursor) {
  int gid = blockIdx.x * 256 + threadIdx.x;
  if (gid < N_NODES) {
    int r = rowptr[gid] + partial[blockIdx.x];
    rowptr[gid] = r;
    cursor[gid] = r;
  }
  if (gid == 0) rowptr[N_NODES] = N_EDGES;
}

__global__ __launch_bounds__(256) void fill_kernel(
    const int* __restrict__ src, const int* __restrict__ dst,
    int* __restrict__ cursor, int* __restrict__ eidx) {
  int e = blockIdx.x * 256 + threadIdx.x;
  if (e >= N_EDGES) return;
  int pos = atomicAdd(&cursor[dst[e]], 1);
  eidx[pos] = src[e];
}

// ---------------------------------------------------------------------------
// Convert x0 (f32) -> bf16.  6.4M elems, float4 -> us4.
// ---------------------------------------------------------------------------
__global__ __launch_bounds__(256) void convert_x(
    const float* __restrict__ x, unsigned short* __restrict__ xb) {
  int i = blockIdx.x * 256 + threadIdx.x;        // float4 index
  if (i >= N_NODES * D_IN / 4) return;
  float4 v = ((const float4*)x)[i];
  us4 p = { f2bf(v.x), f2bf(v.y), f2bf(v.z), f2bf(v.w) };
  ((us4*)xb)[i] = p;
}

// ---------------------------------------------------------------------------
// Aggregation: aggb[n] = xb[n] + sum_{j in CSR[n]} xb[eidx[j]].  No atomics.
// One wave per node (no divergence); lane owns features 2t, 2t+1 (ushort2 =
// 4B/lane -> one 256B coalesced row segment per wave per edge). 4-edge unroll
// for >=8 outstanding loads; f32 accumulation.
// ---------------------------------------------------------------------------
__global__ __launch_bounds__(256) void agg_kernel(
    const unsigned short* __restrict__ xb, const int* __restrict__ rowptr,
    const int* __restrict__ eidx, unsigned short* __restrict__ aggb) {
  int n = blockIdx.x * 4 + (threadIdx.x >> 6);
  if (n >= N_NODES) return;
  int t = threadIdx.x & 63;
  const size_t tt = (size_t)t * 2;
  ushort2 own = *(const ushort2*)&xb[(size_t)n * D_IN + tt];
  float a0 = bf2f(own.x), a1 = bf2f(own.y);
  float c0 = 0.f, c1 = 0.f;
  int j = rowptr[n];
  const int end = rowptr[n + 1];
  for (; j + 3 < end; j += 4) {
    int s0 = eidx[j], s1 = eidx[j + 1], s2 = eidx[j + 2], s3 = eidx[j + 3];
    ushort2 v0 = *(const ushort2*)&xb[(size_t)s0 * D_IN + tt];
    ushort2 v1 = *(const ushort2*)&xb[(size_t)s1 * D_IN + tt];
    ushort2 v2 = *(const ushort2*)&xb[(size_t)s2 * D_IN + tt];
    ushort2 v3 = *(const ushort2*)&xb[(size_t)s3 * D_IN + tt];
    a0 += bf2f(v0.x) + bf2f(v1.x);
    a1 += bf2f(v0.y) + bf2f(v1.y);
    c0 += bf2f(v2.x) + bf2f(v3.x);
    c1 += bf2f(v2.y) + bf2f(v3.y);
  }
  for (; j < end; ++j) {
    int s = eidx[j];
    ushort2 v = *(const ushort2*)&xb[(size_t)s * D_IN + tt];
    a0 += bf2f(v.x);
    a1 += bf2f(v.y);
  }
  a0 += c0; a1 += c1;
  ushort2 r = { f2bf(a0), f2bf(a1) };
  *(ushort2*)&aggb[(size_t)n * D_IN + tt] = r;
}

// ---------------------------------------------------------------------------
// Convert W1 [L][K=128][N=256] and W2 [L][K=256][N=128] (f32) to bf16,
// TRANSPOSED to [L][N][K] so MFMA B-fragments are 16B-contiguous loads.
// ---------------------------------------------------------------------------
__global__ __launch_bounds__(256) void convert_weights(
    const float* __restrict__ W1, const float* __restrict__ W2,
    unsigned short* __restrict__ w1bf, unsigned short* __restrict__ w2bf) {
  int idx = blockIdx.x * 256 + threadIdx.x;
  const int per = LAYERS * D_IN * D_HID;   // 98304 (same count for both)
  if (idx < per) {
    int l = idx / (D_IN * D_HID);
    int r = idx % (D_IN * D_HID);
    int n = r / D_IN;        // 0..255
    int k = r % D_IN;        // 0..127
    w1bf[idx] = f2bf(W1[(size_t)l * D_IN * D_HID + (size_t)k * D_HID + n]);
  } else {
    int j = idx - per;
    if (j < LAYERS * D_HID * D_OUT) {
      int l = j / (D_HID * D_OUT);
      int r = j % (D_HID * D_OUT);
      int n = r / D_HID;     // 0..127
      int k = r % D_HID;     // 0..255
      w2bf[j] = f2bf(W2[(size_t)l * D_HID * D_OUT + (size_t)k * D_OUT + n]);
    }
  }
}

// ---------------------------------------------------------------------------
// MLP layer 1: h = relu(aggb @ W1 + b1).  M=50000, N=256, K=128, bf16 in.
// Block = 256 thr (4 waves), tile 64x256; wave w handles cols [w*64, w*64+64).
// ---------------------------------------------------------------------------
#define LDA1 136
__global__ __launch_bounds__(256) void mlp1_kernel(
    const unsigned short* __restrict__ aggb, const unsigned short* __restrict__ w1,
    const float* __restrict__ b1, unsigned short* __restrict__ h) {
  __shared__ unsigned short As[64 * LDA1];
  const int tid = threadIdx.x;
  const int block_row = blockIdx.x * 64;

  // Stage A: 64 rows x 128 bf16 = 1024 us8 chunks (16 per row).
  for (int k = 0; k < 4; ++k) {
    int j = tid + k * 256;
    int row = j >> 4;
    int c8 = j & 15;
    int node = block_row + row;
    if (node >= N_NODES) node = N_NODES - 1;   // clamp; garbage rows never stored
    us8 v = *(const us8*)&aggb[(size_t)node * D_IN + c8 * 8];
    *(us8*)&As[row * LDA1 + c8 * 8] = v;
  }
  __syncthreads();

  const int wave = tid >> 6;
  const int lane = tid & 63;
  const int lo16 = lane & 15;
  const int hi4  = lane >> 4;
  const int ncol0 = wave * 64;

  f32x4 acc[4][4] = {};
  for (int ks = 0; ks < 4; ++ks) {
    const int koff = ks * 32 + hi4 * 8;
    bf16x8 a[4], b[4];
#pragma unroll
    for (int m = 0; m < 4; ++m)
      a[m] = *(const bf16x8*)&As[(m * 16 + lo16) * LDA1 + koff];
#pragma unroll
    for (int n = 0; n < 4; ++n)
      b[n] = *(const bf16x8*)&w1[(size_t)(ncol0 + n * 16 + lo16) * D_IN + koff];
#pragma unroll
    for (int m = 0; m < 4; ++m)
#pragma unroll
      for (int n = 0; n < 4; ++n)
        acc[m][n] = __builtin_amdgcn_mfma_f32_16x16x32_bf16(a[m], b[n], acc[m][n], 0, 0, 0);
  }

#pragma unroll
  for (int n = 0; n < 4; ++n) {
    int col = ncol0 + n * 16 + lo16;
    float bias = b1[col];
#pragma unroll
    for (int m = 0; m < 4; ++m) {
#pragma unroll
      for (int r = 0; r < 4; ++r) {
        int node = block_row + m * 16 + hi4 * 4 + r;
        if (node < N_NODES) {
          float v = acc[m][n][r] + bias;
          v = v > 0.f ? v : 0.f;
          h[(size_t)node * D_HID + col] = f2bf(v);
        }
      }
    }
  }
}

// ---------------------------------------------------------------------------
// MLP layer 2: out = h @ W2 + b2.  M=50000, N=128, K=256.
// FINAL=true -> f32 out; else bf16 xbuf (feeds next layer's gather).
// ---------------------------------------------------------------------------
#define LDA2 264
template <bool FINAL>
__global__ __launch_bounds__(256) void mlp2_kernel(
    const unsigned short* __restrict__ h, const unsigned short* __restrict__ w2,
    const float* __restrict__ b2, float* __restrict__ outf,
    unsigned short* __restrict__ outb) {
  __shared__ unsigned short As[64 * LDA2];
  const int tid = threadIdx.x;
  const int block_row = blockIdx.x * 64;

  // Stage A: 64 rows x 256 bf16.  2048 us8 (16B) loads, coalesced.
  for (int k = 0; k < 8; ++k) {
    int j = tid + k * 256;
    int row = j >> 5;
    int c8 = j & 31;
    int node = block_row + row;
    if (node >= N_NODES) node = N_NODES - 1;
    us8 v = *(const us8*)&h[(size_t)node * D_HID + c8 * 8];
    *(us8*)&As[row * LDA2 + c8 * 8] = v;
  }
  __syncthreads();

  const int wave = tid >> 6;
  const int lane = tid & 63;
  const int lo16 = lane & 15;
  const int hi4  = lane >> 4;
  const int ncol0 = wave * 32;

  f32x4 acc[4][2] = {};
  for (int ks = 0; ks < 8; ++ks) {
    const int koff = ks * 32 + hi4 * 8;
    bf16x8 a[4], b[2];
#pragma unroll
    for (int m = 0; m < 4; ++m)
      a[m] = *(const bf16x8*)&As[(m * 16 + lo16) * LDA2 + koff];
#pragma unroll
    for (int n = 0; n < 2; ++n)
      b[n] = *(const bf16x8*)&w2[(size_t)(ncol0 + n * 16 + lo16) * D_HID + koff];
#pragma unroll
    for (int m = 0; m < 4; ++m)
#pragma unroll
      for (int n = 0; n < 2; ++n)
        acc[m][n] = __builtin_amdgcn_mfma_f32_16x16x32_bf16(a[m], b[n], acc[m][n], 0, 0, 0);
  }

#pragma unroll
  for (int n = 0; n < 2; ++n) {
    int col = ncol0 + n * 16 + lo16;
    float bias = b2[col];
#pragma unroll
    for (int m = 0; m < 4; ++m) {
#pragma unroll
      for (int r = 0; r < 4; ++r) {
        int node = block_row + m * 16 + hi4 * 4 + r;
        if (node < N_NODES) {
          float v = acc[m][n][r] + bias;
          if (FINAL) outf[(size_t)node * D_OUT + col] = v;
          else       outb[(size_t)node * D_OUT + col] = f2bf(v);
        }
      }
    }
  }
}

// ---------------------------------------------------------------------------
extern "C" void kernel_launch(void* const* d_in, const int* in_sizes, int n_in,
                              void* d_out, int out_size, void* d_ws, size_t ws_size,
                              hipStream_t stream) {
  const float* x0 = (const float*)d_in[0];
  const float* W1 = (const float*)d_in[1];
  const float* b1 = (const float*)d_in[2];
  const float* W2 = (const float*)d_in[3];
  const float* b2 = (const float*)d_in[4];
  const int* src  = (const int*)d_in[5];
  const int* dst  = (const int*)d_in[6];
  float* out = (float*)d_out;

  char* ws = (char*)d_ws;
  size_t off = 0;
  unsigned short* xb   = (unsigned short*)(ws + off); off += (size_t)N_NODES * D_IN * 2;   // 12.8 MB
  unsigned short* aggb = (unsigned short*)(ws + off); off += (size_t)N_NODES * D_IN * 2;   // 12.8 MB
  unsigned short* hbuf = (unsigned short*)(ws + off); off += (size_t)N_NODES * D_HID * 2;  // 25.6 MB
  unsigned short* xbuf = (unsigned short*)(ws + off); off += (size_t)N_NODES * D_OUT * 2;  // 12.8 MB
  unsigned short* w1bf = (unsigned short*)(ws + off); off += (size_t)LAYERS * D_IN * D_HID * 2;
  unsigned short* w2bf = (unsigned short*)(ws + off); off += (size_t)LAYERS * D_HID * D_OUT * 2;
  int* deg     = (int*)(ws + off); off += (size_t)(N_NODES + 1) * 4;
  int* rowptr  = (int*)(ws + off); off += (size_t)(N_NODES + 1) * 4;
  int* cursor  = (int*)(ws + off); off += (size_t)(N_NODES + 1) * 4;
  int* partial = (int*)(ws + off); off += (size_t)SCAN_BLOCKS * 4;
  int* eidx    = (int*)(ws + off); off += (size_t)N_EDGES * 4;       // 3.2 MB

  // --- CSR build (per launch; ws is re-poisoned each call) ---
  hipMemsetAsync(deg, 0, (size_t)N_NODES * 4, stream);
  hist_kernel<<<N_EDGES / 256, 256, 0, stream>>>(dst, deg);
  scan_a_kernel<<<SCAN_BLOCKS, 256, 0, stream>>>(deg, rowptr, partial);
  scan_b_kernel<<<1, 256, 0, stream>>>(partial);
  scan_c_kernel<<<SCAN_BLOCKS, 256, 0, stream>>>(rowptr, partial, cursor);
  fill_kernel<<<N_EDGES / 256, 256, 0, stream>>>(src, dst, cursor, eidx);

  convert_x<<<(N_NODES * D_IN / 4 + 255) / 256, 256, 0, stream>>>(x0, xb);
  convert_weights<<<768, 256, 0, stream>>>(W1, W2, w1bf, w2bf);

  const int grid_mlp = (N_NODES + 63) / 64;   // 782
  const int grid_agg = (N_NODES + 3) / 4;     // 12500
  const unsigned short* xcur = xb;
  for (int l = 0; l < LAYERS; ++l) {
    agg_kernel<<<grid_agg, 256, 0, stream>>>(xcur, rowptr, eidx, aggb);
    mlp1_kernel<<<grid_mlp, 256, 0, stream>>>(
        aggb, w1bf + (size_t)l * D_IN * D_HID, b1 + (size_t)l * D_HID, hbuf);
    if (l == LAYERS - 1) {
      mlp2_kernel<true><<<grid_mlp, 256, 0, stream>>>(
          hbuf, w2bf + (size_t)l * D_HID * D_OUT, b2 + (size_t)l * D_OUT, out, nullptr);
    } else {
      mlp2_kernel<false><<<grid_mlp, 256, 0, stream>>>(
          hbuf, w2bf + (size_t)l * D_HID * D_OUT, b2 + (size_t)l * D_OUT, nullptr, xbuf);
    }
    xcur = xbuf;
  }
}